// Round 1
// baseline (309.919 us; speedup 1.0000x reference)
//
#include <hip/hip_runtime.h>
#include <hip/hip_cooperative_groups.h>
#include <math.h>

namespace cg = cooperative_groups;

#define MM 2049
#define BB 16
#define NN 512
#define JH 1025           // half-spectrum (j = 0..1024)
#define JP 1040           // padded row stride for PSp (float2 units)
#define SZ 8              // s-pair-chunk split in phase 1
#define PCH 128           // pairs per chunk: 8*128 = 1024 pairs (s=1..1024)
#define JCH 5             // j-chunks of 256 (5*256 >= 1025)
#define TCH 5             // t-chunks of 256 (5*256 >= 1025; t in [0,1024])
// legacy (fallback 3-kernel path) phase-2 split
#define Z2 4
#define JB2 257
// fused-kernel phase-2 split: 5*16*8 = 640 blocks, 129-iter rotation chains
#define Z2F 8
#define JBF 129           // 8*129 = 1032 >= 1025
#define GRIDF 640

static constexpr double D_TWO_PI    = 6.283185307179586476925286766559;
static constexpr double D_STEP      = D_TWO_PI / 2049.0;
static constexpr float  F_TWO_PI    = 6.28318530717958647692f;
static constexpr float  INV_4TAU    = 83333.33333333333f;   // 1/(4*3e-6)
static constexpr float  PI_OVER_TAU = 1047197.5511965977f;  // pi/tau
static constexpr float  TWO_TAU     = 6.0e-6f;              // 2*tau
static constexpr float  INV_2PI     = 0.15915494309189533f;
static constexpr float  INV_M       = 1.0f / 2049.0f;
static constexpr float  WINF        = 8.0f;

// ---------------------------------------------------------------------------
// Fused cooperative kernel: spread+DFT1  ->  grid.sync  ->  mid+DFT2
//                           ->  grid.sync ->  gather (16 threads/point).
// Rationale: per-iteration cost is dominated by fixed overhead (256 MiB ws
// poison fill @40us + ~3 dispatch boundaries), not compute (~10us). Fusing
// removes two dispatch boundaries; grid.sync on 640 co-resident blocks is
// cheaper than a kernel launch.
// ---------------------------------------------------------------------------

struct P1S { float LA[PCH]; float LB[PCH]; float2 SD[PCH]; float Lz; };
struct P2S { float4 lab[JBF]; };
union ShU { P1S p1; P2S p2; };

__global__ __launch_bounds__(256, 3)
void k_fused(const float* __restrict__ x,
             const float* __restrict__ mRe0, const float* __restrict__ mIm0,
             const float* __restrict__ mRe1, const float* __restrict__ mIm1,
             float2* __restrict__ PSp, float* __restrict__ irfp,
             float* __restrict__ out) {
    cg::grid_group grid = cg::this_grid();
    __shared__ ShU sh;
    const int flat = blockIdx.x;
    const int tid  = threadIdx.x;

    // ------------------------------- phase 1: spread + DFT1 (s-folded) -----
    {
        const int jc = flat % JCH;
        const int b  = (flat / JCH) % BB;
        const int z  = flat / (JCH * BB);          // 0..7
        const int a0 = 1 + PCH * z;                // A = [a0, a0+PCH-1]
        const int b0 = 2049 - PCH * (z + 1);       // B = mirror (2049-s)
        for (int i = tid; i < PCH; i += 256) { sh.p1.LA[i] = 0.0f; sh.p1.LB[i] = 0.0f; }
        if (tid == 0) sh.p1.Lz = 0.0f;
        __syncthreads();
        for (int n = tid; n < NN; n += 256) {
            float xv = x[b * NN + n];
            float xa = xv * F_TWO_PI;
            float p  = xv * (float)MM;
            int m0 = (int)ceilf(p - WINF);  if (m0 < 0) m0 = 0;
            int m1 = (int)floorf(p + WINF); if (m1 > MM - 1) m1 = MM - 1;
            bool hitA = (m1 >= a0) && (m0 <= a0 + PCH - 1);
            bool hitB = (m1 >= b0) && (m0 <= b0 + PCH - 1);
            bool hit0 = (z == 0) && (m0 == 0);
            if (!(hitA || hitB || hit0)) continue;
            for (int m = m0; m <= m1; ++m) {
                float xg = (float)((double)m * D_STEP);
                float d  = xa - xg;
                float gw = expf(-(d * d) * INV_4TAU);
                unsigned ia = (unsigned)(m - a0);
                unsigned ib = (unsigned)(m - b0);
                if (ia < PCH) atomicAdd(&sh.p1.LA[ia], gw);
                if (ib < PCH) atomicAdd(&sh.p1.LB[ib], gw);
                if (hit0 && m == 0) atomicAdd(&sh.p1.Lz, gw);
            }
        }
        __syncthreads();
        // fold: pair of s=a0+i is s'=2049-a0-i = b0 + (PCH-1-i)
        for (int i = tid; i < PCH; i += 256) {
            float ra = sh.p1.LA[i], rb = sh.p1.LB[PCH - 1 - i];
            sh.p1.SD[i] = make_float2(ra + rb, ra - rb);
        }
        __syncthreads();
        const int j = jc * 256 + tid;
        if (j < JH) {
            float ct, st;   // rotation step e^{i*2pi*j/M}
            { float ang = (float)((double)j * D_STEP); __sincosf(ang, &st, &ct); }
            float c, s;     // phase at s = a0
            { int r0 = (j * a0) % MM; float ph = (float)((double)r0 * D_STEP); __sincosf(ph, &s, &c); }
            float accc = 0.0f, accs = 0.0f;
            #pragma unroll 4
            for (int i = 0; i < PCH; ++i) {
                float2 sd = sh.p1.SD[i];         // LDS broadcast b64
                accc = fmaf(sd.x, c, accc);
                accs = fmaf(sd.y, s, accs);
                float t1 = s * st, t2 = s * ct;
                float cn = fmaf(c, ct, -t1);
                float sn = fmaf(c, st,  t2);
                c = cn; s = sn;
            }
            if (z == 0) accc += sh.p1.Lz;        // s = 0 term (cos=1, sin=0)
            PSp[((size_t)b * SZ + z) * JP + j] = make_float2(accc, accs);
        }
    }
    __threadfence();
    grid.sync();

    // ------------------------ phase 2: mid + DFT2 (t-folded), 8-way j-split -
    {
        const int tc  = flat % TCH;
        const int b   = (flat / TCH) % BB;
        const int zj  = flat / (TCH * BB);         // 0..7
        const int jb0 = zj * JBF;
        const int jb1 = min(jb0 + JBF, JH);
        const int cntj = jb1 - jb0;
        for (int i = tid; i < cntj; i += 256) {
            const int j = jb0 + i;
            float cs = 0.0f, sn = 0.0f;
            const float2* base = PSp + (size_t)b * SZ * JP + j;
            #pragma unroll
            for (int z = 0; z < SZ; ++z) {
                float2 ps = base[(size_t)z * JP];
                cs += ps.x; sn += ps.y;
            }
            const int msh = j + 1024;
            const float jf = (float)j;
            const float d2 = PI_OVER_TAU * expf(jf * jf * TWO_TAU);
            const float fac = (j == 0) ? 1.0f : 2.0f;
            const float sc = INV_2PI * d2 * fac;
            float4 v;
            v.x =  sc * mRe1[msh] * cs;   // A  ch0 (channel swap from ifftshift)
            v.y =  sc * mRe0[msh] * cs;   // A  ch1
            v.z = -sc * mIm1[msh] * sn;   // Bd ch0
            v.w = -sc * mIm0[msh] * sn;   // Bd ch1
            sh.p2.lab[i] = v;
        }
        __syncthreads();
        const int t = tc * 256 + tid;
        if (t < JH) {
            float ct, st;   // rotation step e^{i*2pi*t/M}
            { float ang = (float)((double)t * D_STEP); __sincosf(ang, &st, &ct); }
            float c, s;     // phase at j = jb0
            { int r0 = (t * jb0) % MM; float ph = (float)((double)r0 * D_STEP); __sincosf(ph, &s, &c); }
            float E0 = 0.0f, O0 = 0.0f, E1 = 0.0f, O1 = 0.0f;
            #pragma unroll 4
            for (int i = 0; i < cntj; ++i) {
                float4 v = sh.p2.lab[i];          // LDS broadcast b128
                E0 = fmaf(v.x, c, E0);
                O0 = fmaf(v.z, s, O0);
                E1 = fmaf(v.y, c, E1);
                O1 = fmaf(v.w, s, O1);
                float t1 = s * st, t2 = s * ct;
                float cn = fmaf(c, ct, -t1);
                float sn2 = fmaf(c, st,  t2);
                c = cn; s = sn2;
            }
            float* o = irfp + ((size_t)(zj * BB + b) * MM) * 2;
            o[t * 2 + 0] = (E0 - O0) * INV_M;
            o[t * 2 + 1] = (E1 - O1) * INV_M;
            if (t >= 1) {
                o[(MM - t) * 2 + 0] = (E0 + O0) * INV_M;
                o[(MM - t) * 2 + 1] = (E1 + O1) * INV_M;
            }
        }
    }
    __threadfence();
    grid.sync();

    // ------------------- phase 3: gather, 16 threads/point + shfl reduce ----
    {
        const unsigned gg = (unsigned)flat * 256u + (unsigned)tid;
        const unsigned p  = gg >> 4;               // point index b*NN+n
        const unsigned tt = gg & 15u;              // lane within point group
        if (p < BB * NN) {
            const int b = (int)p / NN;
            float xv = x[p];
            float xa = xv * F_TWO_PI;
            float pp = xv * (float)MM;
            int m0 = (int)ceilf(pp - WINF);  if (m0 < 0) m0 = 0;
            int m1 = (int)floorf(pp + WINF); if (m1 > MM - 1) m1 = MM - 1;
            float acc0 = 0.0f, acc1 = 0.0f;
            for (int m = m0 + (int)tt; m <= m1; m += 16) {
                float xg = (float)((double)m * D_STEP);
                float d  = xa - xg;
                float gw = expf(-(d * d) * INV_4TAU);
                float p0 = 0.0f, p1 = 0.0f;
                #pragma unroll
                for (int z = 0; z < Z2F; ++z) {
                    const float2* base = (const float2*)(irfp + ((size_t)(z * BB + b) * MM) * 2);
                    float2 v = base[m];
                    p0 += v.x;
                    p1 += v.y;
                }
                acc0 = fmaf(gw, p0, acc0);
                acc1 = fmaf(gw, p1, acc1);
            }
            #pragma unroll
            for (int off = 8; off > 0; off >>= 1) {
                acc0 += __shfl_xor(acc0, off);
                acc1 += __shfl_xor(acc1, off);
            }
            if (tt == 0) {
                out[p * 2 + 0] = acc0 * INV_M;
                out[p * 2 + 1] = acc1 * INV_M;
            }
        }
    }
}

// ---------------------------------------------------------------------------
// Fallback path: the previously-verified 3-kernel pipeline (used only if the
// cooperative launch is rejected, e.g. co-residency or capture limitation).
// ---------------------------------------------------------------------------
__global__ void k_sdft1(const float* __restrict__ x, float2* __restrict__ PSp) {
    __shared__ float  LA[PCH];
    __shared__ float  LB[PCH];
    __shared__ float2 SD[PCH];
    __shared__ float  Lz;
    const int b  = blockIdx.y;
    const int z  = blockIdx.z;
    const int a0 = 1 + PCH * z;
    const int b0 = 2049 - PCH * (z + 1);
    for (int i = threadIdx.x; i < PCH; i += 256) { LA[i] = 0.0f; LB[i] = 0.0f; }
    if (threadIdx.x == 0) Lz = 0.0f;
    __syncthreads();
    for (int n = threadIdx.x; n < NN; n += 256) {
        float xv = x[b * NN + n];
        float xa = xv * F_TWO_PI;
        float p  = xv * (float)MM;
        int m0 = (int)ceilf(p - WINF);  if (m0 < 0) m0 = 0;
        int m1 = (int)floorf(p + WINF); if (m1 > MM - 1) m1 = MM - 1;
        bool hitA = (m1 >= a0) && (m0 <= a0 + PCH - 1);
        bool hitB = (m1 >= b0) && (m0 <= b0 + PCH - 1);
        bool hit0 = (z == 0) && (m0 == 0);
        if (!(hitA || hitB || hit0)) continue;
        for (int m = m0; m <= m1; ++m) {
            float xg = (float)((double)m * D_STEP);
            float d  = xa - xg;
            float g  = expf(-(d * d) * INV_4TAU);
            unsigned ia = (unsigned)(m - a0);
            unsigned ib = (unsigned)(m - b0);
            if (ia < PCH) atomicAdd(&LA[ia], g);
            if (ib < PCH) atomicAdd(&LB[ib], g);
            if (hit0 && m == 0) atomicAdd(&Lz, g);
        }
    }
    __syncthreads();
    for (int i = threadIdx.x; i < PCH; i += 256) {
        float ra = LA[i], rb = LB[PCH - 1 - i];
        SD[i] = make_float2(ra + rb, ra - rb);
    }
    __syncthreads();
    const int j = blockIdx.x * 256 + threadIdx.x;
    if (j >= JH) return;
    float ct, st;
    { float ang = (float)((double)j * D_STEP); __sincosf(ang, &st, &ct); }
    float c, s;
    { int r0 = (j * a0) % MM; float ph = (float)((double)r0 * D_STEP); __sincosf(ph, &s, &c); }
    float accc = 0.0f, accs = 0.0f;
    #pragma unroll 4
    for (int i = 0; i < PCH; ++i) {
        float2 sd = SD[i];
        accc = fmaf(sd.x, c, accc);
        accs = fmaf(sd.y, s, accs);
        float t1 = s * st, t2 = s * ct;
        float cn = fmaf(c, ct, -t1);
        float sn = fmaf(c, st,  t2);
        c = cn; s = sn;
    }
    if (z == 0) accc += Lz;
    PSp[((size_t)b * SZ + z) * JP + j] = make_float2(accc, accs);
}

__global__ void k_dft2m(const float2* __restrict__ PSp,
                        const float* __restrict__ mRe0, const float* __restrict__ mIm0,
                        const float* __restrict__ mRe1, const float* __restrict__ mIm1,
                        float* __restrict__ irfp) {
    __shared__ float4 lab[JB2];
    const int b   = blockIdx.y;
    const int zj  = blockIdx.z;
    const int jb0 = zj * JB2;
    const int jb1 = min(jb0 + JB2, JH);
    const int cntj = jb1 - jb0;
    for (int i = threadIdx.x; i < cntj; i += 256) {
        const int j = jb0 + i;
        float cs = 0.0f, sn = 0.0f;
        const float2* base = PSp + (size_t)b * SZ * JP + j;
        #pragma unroll
        for (int z = 0; z < SZ; ++z) {
            float2 ps = base[(size_t)z * JP];
            cs += ps.x; sn += ps.y;
        }
        const int msh = j + 1024;
        const float jf = (float)j;
        const float d2 = PI_OVER_TAU * expf(jf * jf * TWO_TAU);
        const float fac = (j == 0) ? 1.0f : 2.0f;
        const float sc = INV_2PI * d2 * fac;
        float4 v;
        v.x =  sc * mRe1[msh] * cs;
        v.y =  sc * mRe0[msh] * cs;
        v.z = -sc * mIm1[msh] * sn;
        v.w = -sc * mIm0[msh] * sn;
        lab[i] = v;
    }
    __syncthreads();
    const int t = blockIdx.x * 256 + threadIdx.x;
    if (t >= JH) return;
    float ct, st;
    { float ang = (float)((double)t * D_STEP); __sincosf(ang, &st, &ct); }
    float c, s;
    { int r0 = (t * jb0) % MM; float ph = (float)((double)r0 * D_STEP); __sincosf(ph, &s, &c); }
    float E0 = 0.0f, O0 = 0.0f, E1 = 0.0f, O1 = 0.0f;
    #pragma unroll 4
    for (int i = 0; i < cntj; ++i) {
        float4 v = lab[i];
        E0 = fmaf(v.x, c, E0);
        O0 = fmaf(v.z, s, O0);
        E1 = fmaf(v.y, c, E1);
        O1 = fmaf(v.w, s, O1);
        float t1 = s * st, t2 = s * ct;
        float cn = fmaf(c, ct, -t1);
        float sn2 = fmaf(c, st,  t2);
        c = cn; s = sn2;
    }
    float* o = irfp + ((size_t)(zj * BB + b) * MM) * 2;
    o[t * 2 + 0] = (E0 - O0) * INV_M;
    o[t * 2 + 1] = (E1 - O1) * INV_M;
    if (t >= 1) {
        o[(MM - t) * 2 + 0] = (E0 + O0) * INV_M;
        o[(MM - t) * 2 + 1] = (E1 + O1) * INV_M;
    }
}

__global__ void k_gather(const float* __restrict__ x, const float* __restrict__ irfp,
                         float* __restrict__ out) {
    const int idx = blockIdx.x * blockDim.x + threadIdx.x;
    if (idx >= BB * NN) return;
    const int b = idx / NN;
    float xv = x[idx];
    float xa = xv * F_TWO_PI;
    float p  = xv * (float)MM;
    int m0 = (int)ceilf(p - WINF);  if (m0 < 0) m0 = 0;
    int m1 = (int)floorf(p + WINF); if (m1 > MM - 1) m1 = MM - 1;
    float acc0 = 0.0f, acc1 = 0.0f;
    for (int m = m0; m <= m1; ++m) {
        float xg = (float)((double)m * D_STEP);
        float d  = xa - xg;
        float g  = expf(-(d * d) * INV_4TAU);
        float p0 = 0.0f, p1 = 0.0f;
        #pragma unroll
        for (int z = 0; z < Z2; ++z) {
            const float2* base = (const float2*)(irfp + ((size_t)(z * BB + b) * MM) * 2);
            float2 v = base[m];
            p0 += v.x;
            p1 += v.y;
        }
        acc0 = fmaf(g, p0, acc0);
        acc1 = fmaf(g, p1, acc1);
    }
    out[idx * 2 + 0] = acc0 * INV_M;
    out[idx * 2 + 1] = acc1 * INV_M;
}

// ---------------------------------------------------------------- launch ----
extern "C" void kernel_launch(void* const* d_in, const int* in_sizes, int n_in,
                              void* d_out, int out_size, void* d_ws, size_t ws_size,
                              hipStream_t stream) {
    const float* x    = (const float*)d_in[0];
    const float* mRe0 = (const float*)d_in[1];
    const float* mIm0 = (const float*)d_in[2];
    const float* mRe1 = (const float*)d_in[3];
    const float* mIm1 = (const float*)d_in[4];
    float* out = (float*)d_out;

    float2* PSp  = (float2*)d_ws;                              // [BB][SZ][JP] float2
    float*  irfp = (float*)d_ws + (size_t)2 * BB * SZ * JP;    // [Z2F][BB][MM][2]

    void* args[] = { (void*)&x, (void*)&mRe0, (void*)&mIm0, (void*)&mRe1, (void*)&mIm1,
                     (void*)&PSp, (void*)&irfp, (void*)&out };
    hipError_t e = hipLaunchCooperativeKernel((const void*)k_fused, dim3(GRIDF), dim3(256),
                                              (void**)args, 0u, stream);
    if (e != hipSuccess) {
        // fallback: previously-verified 3-kernel pipeline (Z2=4 irfp layout)
        k_sdft1 <<<dim3(JCH, BB, SZ), 256, 0, stream>>>(x, PSp);
        k_dft2m <<<dim3(TCH, BB, Z2), 256, 0, stream>>>(PSp, mRe0, mIm0, mRe1, mIm1, irfp);
        k_gather<<<(BB * NN + 255) / 256, 256, 0, stream>>>(x, irfp, out);
    }
}

// Round 2
// 300.055 us; speedup vs baseline: 1.0329x; 1.0329x over previous
//
#include <hip/hip_runtime.h>
#include <math.h>

#define MM 2049
#define BB 16
#define NN 512
#define JH 1025           // half-spectrum (j = 0..1024)
#define JP 1040           // padded row stride for PSp (float2 units)
#define SZ 8              // s-pair-chunk split in phase 1
#define PCH 128           // pairs per chunk: 8*128 = 1024 pairs (s=1..1024)
#define JCH 5             // j-chunks of 256 (5*256 >= 1025)
#define TCH 5             // t-chunks of 256 (5*256 >= 1025; t in [0,1024])
// legacy (fallback 3-kernel path) phase-2 split
#define Z2 4
#define JB2 257
// fused-kernel phase-2 split: 5*16*8 = 640 blocks, 129-iter rotation chains
#define Z2F 8
#define JBF 129           // 8*129 = 1032 >= 1025
#define GRIDF 640

static constexpr double D_TWO_PI    = 6.283185307179586476925286766559;
static constexpr double D_STEP      = D_TWO_PI / 2049.0;
static constexpr float  F_TWO_PI    = 6.28318530717958647692f;
static constexpr float  INV_4TAU    = 83333.33333333333f;   // 1/(4*3e-6)
static constexpr float  PI_OVER_TAU = 1047197.5511965977f;  // pi/tau
static constexpr float  TWO_TAU     = 6.0e-6f;              // 2*tau
static constexpr float  INV_2PI     = 0.15915494309189533f;
static constexpr float  INV_M       = 1.0f / 2049.0f;
static constexpr float  WINF        = 8.0f;

// ---------------------------------------------------------------------------
// Custom lightweight grid barrier.
// Round-1 post-mortem: cg::grid.sync() cost ~112 us per sync (k_fused 234 us,
// VALUBusy 3.6% => ~225 us pure spin). Replace with a generation-counting
// barrier on __device__ globals (persist across graph replays; leaves
// count=0 and gen monotonically increasing => replay-safe). Cooperative
// launch is kept ONLY for the co-residency guarantee; grid.sync is unused.
// __threadfence() before arrival writes back the block's dirty L2 lines
// (agent-scope release); after the spin it invalidates (acquire) so all
// threads see other XCDs' writes. Dirty data is <1 MB => fences are cheap.
// ---------------------------------------------------------------------------
__device__ unsigned g_bar_count = 0;
__device__ unsigned g_bar_gen   = 0;

__device__ __forceinline__ void grid_barrier(unsigned nblocks) {
    __syncthreads();
    if (threadIdx.x == 0) {
        __threadfence();   // release: write back this block's stores
        unsigned gen = __hip_atomic_load(&g_bar_gen, __ATOMIC_RELAXED,
                                         __HIP_MEMORY_SCOPE_AGENT);
        unsigned prev = __hip_atomic_fetch_add(&g_bar_count, 1u, __ATOMIC_ACQ_REL,
                                               __HIP_MEMORY_SCOPE_AGENT);
        if (prev + 1u == nblocks) {
            __hip_atomic_store(&g_bar_count, 0u, __ATOMIC_RELAXED,
                               __HIP_MEMORY_SCOPE_AGENT);
            __hip_atomic_fetch_add(&g_bar_gen, 1u, __ATOMIC_RELEASE,
                                   __HIP_MEMORY_SCOPE_AGENT);
        } else {
            while (__hip_atomic_load(&g_bar_gen, __ATOMIC_ACQUIRE,
                                     __HIP_MEMORY_SCOPE_AGENT) == gen) {
                __builtin_amdgcn_s_sleep(2);
            }
        }
        __threadfence();   // acquire: invalidate so we see other blocks' stores
    }
    __syncthreads();
}

// ---------------------------------------------------------------------------
// Fused kernel: spread+DFT1 -> barrier -> mid+DFT2 -> barrier -> gather.
// ---------------------------------------------------------------------------

struct P1S { float LA[PCH]; float LB[PCH]; float2 SD[PCH]; float Lz; };
struct P2S { float4 lab[JBF]; };
union ShU { P1S p1; P2S p2; };

__global__ __launch_bounds__(256, 3)
void k_fused(const float* __restrict__ x,
             const float* __restrict__ mRe0, const float* __restrict__ mIm0,
             const float* __restrict__ mRe1, const float* __restrict__ mIm1,
             float2* __restrict__ PSp, float* __restrict__ irfp,
             float* __restrict__ out) {
    __shared__ ShU sh;
    const int flat = blockIdx.x;
    const int tid  = threadIdx.x;

    // ------------------------------- phase 1: spread + DFT1 (s-folded) -----
    {
        const int jc = flat % JCH;
        const int b  = (flat / JCH) % BB;
        const int z  = flat / (JCH * BB);          // 0..7
        const int a0 = 1 + PCH * z;                // A = [a0, a0+PCH-1]
        const int b0 = 2049 - PCH * (z + 1);       // B = mirror (2049-s)
        for (int i = tid; i < PCH; i += 256) { sh.p1.LA[i] = 0.0f; sh.p1.LB[i] = 0.0f; }
        if (tid == 0) sh.p1.Lz = 0.0f;
        __syncthreads();
        for (int n = tid; n < NN; n += 256) {
            float xv = x[b * NN + n];
            float xa = xv * F_TWO_PI;
            float p  = xv * (float)MM;
            int m0 = (int)ceilf(p - WINF);  if (m0 < 0) m0 = 0;
            int m1 = (int)floorf(p + WINF); if (m1 > MM - 1) m1 = MM - 1;
            bool hitA = (m1 >= a0) && (m0 <= a0 + PCH - 1);
            bool hitB = (m1 >= b0) && (m0 <= b0 + PCH - 1);
            bool hit0 = (z == 0) && (m0 == 0);
            if (!(hitA || hitB || hit0)) continue;
            for (int m = m0; m <= m1; ++m) {
                float xg = (float)((double)m * D_STEP);
                float d  = xa - xg;
                float gw = expf(-(d * d) * INV_4TAU);
                unsigned ia = (unsigned)(m - a0);
                unsigned ib = (unsigned)(m - b0);
                if (ia < PCH) atomicAdd(&sh.p1.LA[ia], gw);
                if (ib < PCH) atomicAdd(&sh.p1.LB[ib], gw);
                if (hit0 && m == 0) atomicAdd(&sh.p1.Lz, gw);
            }
        }
        __syncthreads();
        // fold: pair of s=a0+i is s'=2049-a0-i = b0 + (PCH-1-i)
        for (int i = tid; i < PCH; i += 256) {
            float ra = sh.p1.LA[i], rb = sh.p1.LB[PCH - 1 - i];
            sh.p1.SD[i] = make_float2(ra + rb, ra - rb);
        }
        __syncthreads();
        const int j = jc * 256 + tid;
        if (j < JH) {
            float ct, st;   // rotation step e^{i*2pi*j/M}
            { float ang = (float)((double)j * D_STEP); __sincosf(ang, &st, &ct); }
            float c, s;     // phase at s = a0
            { int r0 = (j * a0) % MM; float ph = (float)((double)r0 * D_STEP); __sincosf(ph, &s, &c); }
            float accc = 0.0f, accs = 0.0f;
            #pragma unroll 4
            for (int i = 0; i < PCH; ++i) {
                float2 sd = sh.p1.SD[i];         // LDS broadcast b64
                accc = fmaf(sd.x, c, accc);
                accs = fmaf(sd.y, s, accs);
                float t1 = s * st, t2 = s * ct;
                float cn = fmaf(c, ct, -t1);
                float sn = fmaf(c, st,  t2);
                c = cn; s = sn;
            }
            if (z == 0) accc += sh.p1.Lz;        // s = 0 term (cos=1, sin=0)
            PSp[((size_t)b * SZ + z) * JP + j] = make_float2(accc, accs);
        }
    }
    grid_barrier(GRIDF);

    // ------------------------ phase 2: mid + DFT2 (t-folded), 8-way j-split -
    {
        const int tc  = flat % TCH;
        const int b   = (flat / TCH) % BB;
        const int zj  = flat / (TCH * BB);         // 0..7
        const int jb0 = zj * JBF;
        const int jb1 = min(jb0 + JBF, JH);
        const int cntj = jb1 - jb0;
        for (int i = tid; i < cntj; i += 256) {
            const int j = jb0 + i;
            float cs = 0.0f, sn = 0.0f;
            const float2* base = PSp + (size_t)b * SZ * JP + j;
            #pragma unroll
            for (int z = 0; z < SZ; ++z) {
                float2 ps = base[(size_t)z * JP];
                cs += ps.x; sn += ps.y;
            }
            const int msh = j + 1024;
            const float jf = (float)j;
            const float d2 = PI_OVER_TAU * expf(jf * jf * TWO_TAU);
            const float fac = (j == 0) ? 1.0f : 2.0f;
            const float sc = INV_2PI * d2 * fac;
            float4 v;
            v.x =  sc * mRe1[msh] * cs;   // A  ch0 (channel swap from ifftshift)
            v.y =  sc * mRe0[msh] * cs;   // A  ch1
            v.z = -sc * mIm1[msh] * sn;   // Bd ch0
            v.w = -sc * mIm0[msh] * sn;   // Bd ch1
            sh.p2.lab[i] = v;
        }
        __syncthreads();
        const int t = tc * 256 + tid;
        if (t < JH) {
            float ct, st;   // rotation step e^{i*2pi*t/M}
            { float ang = (float)((double)t * D_STEP); __sincosf(ang, &st, &ct); }
            float c, s;     // phase at j = jb0
            { int r0 = (t * jb0) % MM; float ph = (float)((double)r0 * D_STEP); __sincosf(ph, &s, &c); }
            float E0 = 0.0f, O0 = 0.0f, E1 = 0.0f, O1 = 0.0f;
            #pragma unroll 4
            for (int i = 0; i < cntj; ++i) {
                float4 v = sh.p2.lab[i];          // LDS broadcast b128
                E0 = fmaf(v.x, c, E0);
                O0 = fmaf(v.z, s, O0);
                E1 = fmaf(v.y, c, E1);
                O1 = fmaf(v.w, s, O1);
                float t1 = s * st, t2 = s * ct;
                float cn = fmaf(c, ct, -t1);
                float sn2 = fmaf(c, st,  t2);
                c = cn; s = sn2;
            }
            float* o = irfp + ((size_t)(zj * BB + b) * MM) * 2;
            o[t * 2 + 0] = (E0 - O0) * INV_M;
            o[t * 2 + 1] = (E1 - O1) * INV_M;
            if (t >= 1) {
                o[(MM - t) * 2 + 0] = (E0 + O0) * INV_M;
                o[(MM - t) * 2 + 1] = (E1 + O1) * INV_M;
            }
        }
    }
    grid_barrier(GRIDF);

    // ------------------- phase 3: gather, 16 threads/point + shfl reduce ----
    {
        const unsigned gg = (unsigned)flat * 256u + (unsigned)tid;
        const unsigned p  = gg >> 4;               // point index b*NN+n
        const unsigned tt = gg & 15u;              // lane within point group
        if (p < BB * NN) {
            const int b = (int)p / NN;
            float xv = x[p];
            float xa = xv * F_TWO_PI;
            float pp = xv * (float)MM;
            int m0 = (int)ceilf(pp - WINF);  if (m0 < 0) m0 = 0;
            int m1 = (int)floorf(pp + WINF); if (m1 > MM - 1) m1 = MM - 1;
            float acc0 = 0.0f, acc1 = 0.0f;
            for (int m = m0 + (int)tt; m <= m1; m += 16) {
                float xg = (float)((double)m * D_STEP);
                float d  = xa - xg;
                float gw = expf(-(d * d) * INV_4TAU);
                float p0 = 0.0f, p1 = 0.0f;
                #pragma unroll
                for (int z = 0; z < Z2F; ++z) {
                    const float2* base = (const float2*)(irfp + ((size_t)(z * BB + b) * MM) * 2);
                    float2 v = base[m];
                    p0 += v.x;
                    p1 += v.y;
                }
                acc0 = fmaf(gw, p0, acc0);
                acc1 = fmaf(gw, p1, acc1);
            }
            #pragma unroll
            for (int off = 8; off > 0; off >>= 1) {
                acc0 += __shfl_xor(acc0, off);
                acc1 += __shfl_xor(acc1, off);
            }
            if (tt == 0) {
                out[p * 2 + 0] = acc0 * INV_M;
                out[p * 2 + 1] = acc1 * INV_M;
            }
        }
    }
}

// ---------------------------------------------------------------------------
// Fallback path: the previously-verified 3-kernel pipeline (used only if the
// cooperative launch is rejected).
// ---------------------------------------------------------------------------
__global__ void k_sdft1(const float* __restrict__ x, float2* __restrict__ PSp) {
    __shared__ float  LA[PCH];
    __shared__ float  LB[PCH];
    __shared__ float2 SD[PCH];
    __shared__ float  Lz;
    const int b  = blockIdx.y;
    const int z  = blockIdx.z;
    const int a0 = 1 + PCH * z;
    const int b0 = 2049 - PCH * (z + 1);
    for (int i = threadIdx.x; i < PCH; i += 256) { LA[i] = 0.0f; LB[i] = 0.0f; }
    if (threadIdx.x == 0) Lz = 0.0f;
    __syncthreads();
    for (int n = threadIdx.x; n < NN; n += 256) {
        float xv = x[b * NN + n];
        float xa = xv * F_TWO_PI;
        float p  = xv * (float)MM;
        int m0 = (int)ceilf(p - WINF);  if (m0 < 0) m0 = 0;
        int m1 = (int)floorf(p + WINF); if (m1 > MM - 1) m1 = MM - 1;
        bool hitA = (m1 >= a0) && (m0 <= a0 + PCH - 1);
        bool hitB = (m1 >= b0) && (m0 <= b0 + PCH - 1);
        bool hit0 = (z == 0) && (m0 == 0);
        if (!(hitA || hitB || hit0)) continue;
        for (int m = m0; m <= m1; ++m) {
            float xg = (float)((double)m * D_STEP);
            float d  = xa - xg;
            float g  = expf(-(d * d) * INV_4TAU);
            unsigned ia = (unsigned)(m - a0);
            unsigned ib = (unsigned)(m - b0);
            if (ia < PCH) atomicAdd(&LA[ia], g);
            if (ib < PCH) atomicAdd(&LB[ib], g);
            if (hit0 && m == 0) atomicAdd(&Lz, g);
        }
    }
    __syncthreads();
    for (int i = threadIdx.x; i < PCH; i += 256) {
        float ra = LA[i], rb = LB[PCH - 1 - i];
        SD[i] = make_float2(ra + rb, ra - rb);
    }
    __syncthreads();
    const int j = blockIdx.x * 256 + threadIdx.x;
    if (j >= JH) return;
    float ct, st;
    { float ang = (float)((double)j * D_STEP); __sincosf(ang, &st, &ct); }
    float c, s;
    { int r0 = (j * a0) % MM; float ph = (float)((double)r0 * D_STEP); __sincosf(ph, &s, &c); }
    float accc = 0.0f, accs = 0.0f;
    #pragma unroll 4
    for (int i = 0; i < PCH; ++i) {
        float2 sd = SD[i];
        accc = fmaf(sd.x, c, accc);
        accs = fmaf(sd.y, s, accs);
        float t1 = s * st, t2 = s * ct;
        float cn = fmaf(c, ct, -t1);
        float sn = fmaf(c, st,  t2);
        c = cn; s = sn;
    }
    if (z == 0) accc += Lz;
    PSp[((size_t)b * SZ + z) * JP + j] = make_float2(accc, accs);
}

__global__ void k_dft2m(const float2* __restrict__ PSp,
                        const float* __restrict__ mRe0, const float* __restrict__ mIm0,
                        const float* __restrict__ mRe1, const float* __restrict__ mIm1,
                        float* __restrict__ irfp) {
    __shared__ float4 lab[JB2];
    const int b   = blockIdx.y;
    const int zj  = blockIdx.z;
    const int jb0 = zj * JB2;
    const int jb1 = min(jb0 + JB2, JH);
    const int cntj = jb1 - jb0;
    for (int i = threadIdx.x; i < cntj; i += 256) {
        const int j = jb0 + i;
        float cs = 0.0f, sn = 0.0f;
        const float2* base = PSp + (size_t)b * SZ * JP + j;
        #pragma unroll
        for (int z = 0; z < SZ; ++z) {
            float2 ps = base[(size_t)z * JP];
            cs += ps.x; sn += ps.y;
        }
        const int msh = j + 1024;
        const float jf = (float)j;
        const float d2 = PI_OVER_TAU * expf(jf * jf * TWO_TAU);
        const float fac = (j == 0) ? 1.0f : 2.0f;
        const float sc = INV_2PI * d2 * fac;
        float4 v;
        v.x =  sc * mRe1[msh] * cs;
        v.y =  sc * mRe0[msh] * cs;
        v.z = -sc * mIm1[msh] * sn;
        v.w = -sc * mIm0[msh] * sn;
        lab[i] = v;
    }
    __syncthreads();
    const int t = blockIdx.x * 256 + threadIdx.x;
    if (t >= JH) return;
    float ct, st;
    { float ang = (float)((double)t * D_STEP); __sincosf(ang, &st, &ct); }
    float c, s;
    { int r0 = (t * jb0) % MM; float ph = (float)((double)r0 * D_STEP); __sincosf(ph, &s, &c); }
    float E0 = 0.0f, O0 = 0.0f, E1 = 0.0f, O1 = 0.0f;
    #pragma unroll 4
    for (int i = 0; i < cntj; ++i) {
        float4 v = lab[i];
        E0 = fmaf(v.x, c, E0);
        O0 = fmaf(v.z, s, O0);
        E1 = fmaf(v.y, c, E1);
        O1 = fmaf(v.w, s, O1);
        float t1 = s * st, t2 = s * ct;
        float cn = fmaf(c, ct, -t1);
        float sn2 = fmaf(c, st,  t2);
        c = cn; s = sn2;
    }
    float* o = irfp + ((size_t)(zj * BB + b) * MM) * 2;
    o[t * 2 + 0] = (E0 - O0) * INV_M;
    o[t * 2 + 1] = (E1 - O1) * INV_M;
    if (t >= 1) {
        o[(MM - t) * 2 + 0] = (E0 + O0) * INV_M;
        o[(MM - t) * 2 + 1] = (E1 + O1) * INV_M;
    }
}

__global__ void k_gather(const float* __restrict__ x, const float* __restrict__ irfp,
                         float* __restrict__ out) {
    const int idx = blockIdx.x * blockDim.x + threadIdx.x;
    if (idx >= BB * NN) return;
    const int b = idx / NN;
    float xv = x[idx];
    float xa = xv * F_TWO_PI;
    float p  = xv * (float)MM;
    int m0 = (int)ceilf(p - WINF);  if (m0 < 0) m0 = 0;
    int m1 = (int)floorf(p + WINF); if (m1 > MM - 1) m1 = MM - 1;
    float acc0 = 0.0f, acc1 = 0.0f;
    for (int m = m0; m <= m1; ++m) {
        float xg = (float)((double)m * D_STEP);
        float d  = xa - xg;
        float g  = expf(-(d * d) * INV_4TAU);
        float p0 = 0.0f, p1 = 0.0f;
        #pragma unroll
        for (int z = 0; z < Z2; ++z) {
            const float2* base = (const float2*)(irfp + ((size_t)(z * BB + b) * MM) * 2);
            float2 v = base[m];
            p0 += v.x;
            p1 += v.y;
        }
        acc0 = fmaf(g, p0, acc0);
        acc1 = fmaf(g, p1, acc1);
    }
    out[idx * 2 + 0] = acc0 * INV_M;
    out[idx * 2 + 1] = acc1 * INV_M;
}

// ---------------------------------------------------------------- launch ----
extern "C" void kernel_launch(void* const* d_in, const int* in_sizes, int n_in,
                              void* d_out, int out_size, void* d_ws, size_t ws_size,
                              hipStream_t stream) {
    const float* x    = (const float*)d_in[0];
    const float* mRe0 = (const float*)d_in[1];
    const float* mIm0 = (const float*)d_in[2];
    const float* mRe1 = (const float*)d_in[3];
    const float* mIm1 = (const float*)d_in[4];
    float* out = (float*)d_out;

    float2* PSp  = (float2*)d_ws;                              // [BB][SZ][JP] float2
    float*  irfp = (float*)d_ws + (size_t)2 * BB * SZ * JP;    // [Z2F][BB][MM][2]

    void* args[] = { (void*)&x, (void*)&mRe0, (void*)&mIm0, (void*)&mRe1, (void*)&mIm1,
                     (void*)&PSp, (void*)&irfp, (void*)&out };
    hipError_t e = hipLaunchCooperativeKernel((const void*)k_fused, dim3(GRIDF), dim3(256),
                                              (void**)args, 0u, stream);
    if (e != hipSuccess) {
        // fallback: previously-verified 3-kernel pipeline (Z2=4 irfp layout)
        k_sdft1 <<<dim3(JCH, BB, SZ), 256, 0, stream>>>(x, PSp);
        k_dft2m <<<dim3(TCH, BB, Z2), 256, 0, stream>>>(PSp, mRe0, mIm0, mRe1, mIm1, irfp);
        k_gather<<<(BB * NN + 255) / 256, 256, 0, stream>>>(x, irfp, out);
    }
}

// Round 3
// 106.171 us; speedup vs baseline: 2.9191x; 2.8262x over previous
//
#include <hip/hip_runtime.h>
#include <math.h>

#define MM 2049
#define BB 16
#define NN 512
#define JH 1025           // half-spectrum (j = 0..1024)
#define JP 1040           // padded row stride for PSp (float2 units)
#define SZ 8              // s-pair-chunk split in phase 1
#define PCH 128           // pairs per chunk: 8*128 = 1024 pairs (s=1..1024)
#define JCH 5             // j-chunks of 256 (5*256 >= 1025)
#define CT2 205           // t-chunk size in k_dft2g: 5*205 = 1025 exactly
#define TCH2 5            // number of t-chunks

static constexpr double D_TWO_PI    = 6.283185307179586476925286766559;
static constexpr double D_STEP      = D_TWO_PI / 2049.0;
static constexpr float  F_TWO_PI    = 6.28318530717958647692f;
static constexpr float  INV_4TAU    = 83333.33333333333f;   // 1/(4*3e-6)
static constexpr float  PI_OVER_TAU = 1047197.5511965977f;  // pi/tau
static constexpr float  TWO_TAU     = 6.0e-6f;              // 2*tau
static constexpr float  INV_2PI     = 0.15915494309189533f;
static constexpr float  INV_M       = 1.0f / 2049.0f;
static constexpr float  WINF        = 8.0f;

// ---------------------------------------------------------------------------
// Round-2 post-mortem: in-kernel grid sync on gfx950 costs ~110 us PER SYNC
// regardless of implementation (cg::grid.sync 234 us total, custom
// atomic+sense barrier 224 us total, VALUBusy ~3.8% in both) — agent-scope
// acquire/release across 8 non-coherent XCD L2s + 640 spinners on one hot
// line is structurally expensive. Cross-phase dependencies must cross a
// DISPATCH boundary instead.
//
// New structure (2 kernels, down from 3):
//   k_sdft1 : spread + DFT1 (s-symmetry folded)  [unchanged, verified]
//             + zeroes `out` (so k_dft2g can atomicAdd into it)
//   k_dft2g : mid + DFT2 with each block owning a FULL t-chunk (complete
//             j-sum -> final irf values in LDS, no cross-block partials)
//             + fused gather: the block gathers every point whose window
//             overlaps its m-range {t} u {M-t} and atomicAdds into out.
// This removes one kernel + one inter-dispatch gap. Global float atomicAdd
// is device-scope by default (coherent across XCDs).
// ---------------------------------------------------------------------------

// ------------------------------------- spread + DFT1 (s-symmetry folded) ----
__global__ void k_sdft1(const float* __restrict__ x, float2* __restrict__ PSp,
                        float* __restrict__ out) {
    __shared__ float  LA[PCH];
    __shared__ float  LB[PCH];
    __shared__ float2 SD[PCH];   // {sum, diff}
    __shared__ float  Lz;        // red[0] (z==0 only)
    const int b  = blockIdx.y;
    const int z  = blockIdx.z;
    const int a0 = 1 + PCH * z;            // A = [a0, a0+PCH-1]  subset of [1,1024]
    const int b0 = 2049 - PCH * (z + 1);   // B = [b0, b0+PCH-1]  mirror (2049-s)
    // zero the output slice for batch b (k_dft2g accumulates with atomics).
    // One designated block per b; visible to k_dft2g via the dispatch boundary.
    if (blockIdx.x == 0 && z == 0) {
        for (int i = threadIdx.x; i < NN * 2; i += 256) out[b * NN * 2 + i] = 0.0f;
    }
    for (int i = threadIdx.x; i < PCH; i += 256) { LA[i] = 0.0f; LB[i] = 0.0f; }
    if (threadIdx.x == 0) Lz = 0.0f;
    __syncthreads();
    for (int n = threadIdx.x; n < NN; n += 256) {
        float xv = x[b * NN + n];
        float xa = xv * F_TWO_PI;
        float p  = xv * (float)MM;
        int m0 = (int)ceilf(p - WINF);  if (m0 < 0) m0 = 0;
        int m1 = (int)floorf(p + WINF); if (m1 > MM - 1) m1 = MM - 1;
        bool hitA = (m1 >= a0) && (m0 <= a0 + PCH - 1);
        bool hitB = (m1 >= b0) && (m0 <= b0 + PCH - 1);
        bool hit0 = (z == 0) && (m0 == 0);
        if (!(hitA || hitB || hit0)) continue;
        for (int m = m0; m <= m1; ++m) {
            float xg = (float)((double)m * D_STEP);
            float d  = xa - xg;
            float g  = expf(-(d * d) * INV_4TAU);
            unsigned ia = (unsigned)(m - a0);
            unsigned ib = (unsigned)(m - b0);
            if (ia < PCH) atomicAdd(&LA[ia], g);
            if (ib < PCH) atomicAdd(&LB[ib], g);
            if (hit0 && m == 0) atomicAdd(&Lz, g);
        }
    }
    __syncthreads();
    // fold: pair of s=a0+i is s'=2049-a0-i = b0 + (PCH-1-i)
    for (int i = threadIdx.x; i < PCH; i += 256) {
        float ra = LA[i], rb = LB[PCH - 1 - i];
        SD[i] = make_float2(ra + rb, ra - rb);
    }
    __syncthreads();
    const int j = blockIdx.x * 256 + threadIdx.x;
    if (j >= JH) return;
    float ct, st;   // rotation step e^{i*2pi*j/M}
    { float ang = (float)((double)j * D_STEP); __sincosf(ang, &st, &ct); }
    float c, s;     // phase at s = a0
    { int r0 = (j * a0) % MM; float ph = (float)((double)r0 * D_STEP); __sincosf(ph, &s, &c); }
    float accc = 0.0f, accs = 0.0f;
    #pragma unroll 4
    for (int i = 0; i < PCH; ++i) {
        float2 sd = SD[i];                  // LDS broadcast b64
        accc = fmaf(sd.x, c, accc);
        accs = fmaf(sd.y, s, accs);
        float t1 = s * st, t2 = s * ct;
        float cn = fmaf(c, ct, -t1);
        float sn = fmaf(c, st,  t2);
        c = cn; s = sn;
    }
    if (z == 0) accc += Lz;                 // s = 0 term (cos=1, sin=0)
    PSp[((size_t)b * SZ + z) * JP + j] = make_float2(accc, accs);
}

// --------------------- mid + DFT2 (full j-sum per t-chunk) + fused gather ----
// Block (tc, b): t in [tc*205, tc*205+204].  Computes FINAL
//   irf[m=t]   = (E - O)/M,   irf[m=M-t] = (E + O)/M     (per channel)
// into LDS, then gathers all points of batch b whose windows overlap
// L = [t0, t0+204] or H = [M-(t0+204), M-max(t0,1)] and atomicAdds into out.
__global__ __launch_bounds__(256)
void k_dft2g(const float2* __restrict__ PSp,
             const float* __restrict__ mRe0, const float* __restrict__ mIm0,
             const float* __restrict__ mRe1, const float* __restrict__ mIm1,
             const float* __restrict__ x, float* __restrict__ out) {
    __shared__ float4 lab[JH];       // 16400 B: {A0, A1, Bd0, Bd1} per j
    __shared__ float2 irfL[CT2];     // irf at m = t0+i       (ch0, ch1)
    __shared__ float2 irfH[CT2];     // irf at m = MM-(t0+i)  (ch0, ch1)
    const int tc  = blockIdx.x;      // 0..4
    const int b   = blockIdx.y;      // 0..15
    const int t0  = tc * CT2;
    const int tid = threadIdx.x;

    // stage weighted spectral coefficients (fold the 8 s-partials, apply
    // deconv^2 * mult channel-swapped) for ALL j
    for (int i = tid; i < JH; i += 256) {
        const int j = i;
        float cs = 0.0f, sn = 0.0f;
        const float2* base = PSp + (size_t)b * SZ * JP + j;
        #pragma unroll
        for (int z = 0; z < SZ; ++z) {
            float2 ps = base[(size_t)z * JP];
            cs += ps.x; sn += ps.y;
        }
        const int msh = j + 1024;
        const float jf = (float)j;
        const float d2 = PI_OVER_TAU * expf(jf * jf * TWO_TAU);
        const float fac = (j == 0) ? 1.0f : 2.0f;
        const float sc = INV_2PI * d2 * fac;
        float4 v;
        v.x =  sc * mRe1[msh] * cs;   // A  ch0 (channel swap from ifftshift)
        v.y =  sc * mRe0[msh] * cs;   // A  ch1
        v.z = -sc * mIm1[msh] * sn;   // Bd ch0
        v.w = -sc * mIm0[msh] * sn;   // Bd ch1
        lab[i] = v;
    }
    __syncthreads();

    if (tid < CT2) {
        const int t = t0 + tid;
        float ct, st;   // rotation step e^{i*2pi*t/M}
        { float ang = (float)((double)t * D_STEP); __sincosf(ang, &st, &ct); }
        float E0 = 0.0f, O0 = 0.0f, E1 = 0.0f, O1 = 0.0f;
        // full j-sum, rotation re-seeded every 128 steps (keeps roundoff at
        // the verified 129-chain level)
        for (int q0 = 0; q0 < JH; q0 += 128) {
            const int qe = min(q0 + 128, JH);
            float c, s;
            { int r0 = (t * q0) % MM; float ph = (float)((double)r0 * D_STEP); __sincosf(ph, &s, &c); }
            #pragma unroll 4
            for (int i = q0; i < qe; ++i) {
                float4 v = lab[i];              // LDS broadcast b128
                E0 = fmaf(v.x, c, E0);
                O0 = fmaf(v.z, s, O0);
                E1 = fmaf(v.y, c, E1);
                O1 = fmaf(v.w, s, O1);
                float t1 = s * st, t2 = s * ct;
                float cn = fmaf(c, ct, -t1);
                float sn2 = fmaf(c, st,  t2);
                c = cn; s = sn2;
            }
        }
        irfL[tid] = make_float2((E0 - O0) * INV_M, (E1 - O1) * INV_M);
        irfH[tid] = make_float2((E0 + O0) * INV_M, (E1 + O1) * INV_M); // m = MM-t (t>=1)
    }
    __syncthreads();

    // fused gather over this block's m-ownership
    const int L0 = t0, L1 = t0 + CT2 - 1;               // m = t
    const int H0 = MM - L1, H1 = MM - max(t0, 1);       // m = MM - t, t >= 1
    for (int n = tid; n < NN; n += 256) {
        const int p = b * NN + n;
        float xv = x[p];
        float xa = xv * F_TWO_PI;
        float pp = xv * (float)MM;
        int m0 = (int)ceilf(pp - WINF);  if (m0 < 0) m0 = 0;
        int m1 = (int)floorf(pp + WINF); if (m1 > MM - 1) m1 = MM - 1;
        float a0 = 0.0f, a1 = 0.0f;
        int lo = max(m0, L0), hi = min(m1, L1);
        for (int m = lo; m <= hi; ++m) {
            float xg = (float)((double)m * D_STEP);
            float d  = xa - xg;
            float g  = expf(-(d * d) * INV_4TAU);
            float2 v = irfL[m - L0];
            a0 = fmaf(g, v.x, a0);
            a1 = fmaf(g, v.y, a1);
        }
        int lo2 = max(m0, H0), hi2 = min(m1, H1);
        for (int m = lo2; m <= hi2; ++m) {
            float xg = (float)((double)m * D_STEP);
            float d  = xa - xg;
            float g  = expf(-(d * d) * INV_4TAU);
            float2 v = irfH[(MM - m) - t0];
            a0 = fmaf(g, v.x, a0);
            a1 = fmaf(g, v.y, a1);
        }
        if ((hi >= lo) || (hi2 >= lo2)) {
            atomicAdd(&out[p * 2 + 0], a0 * INV_M);
            atomicAdd(&out[p * 2 + 1], a1 * INV_M);
        }
    }
}

// ---------------------------------------------------------------- launch ----
extern "C" void kernel_launch(void* const* d_in, const int* in_sizes, int n_in,
                              void* d_out, int out_size, void* d_ws, size_t ws_size,
                              hipStream_t stream) {
    const float* x    = (const float*)d_in[0];
    const float* mRe0 = (const float*)d_in[1];
    const float* mIm0 = (const float*)d_in[2];
    const float* mRe1 = (const float*)d_in[3];
    const float* mIm1 = (const float*)d_in[4];
    float* out = (float*)d_out;

    float2* PSp = (float2*)d_ws;    // [BB][SZ][JP] float2

    k_sdft1<<<dim3(JCH, BB, SZ), 256, 0, stream>>>(x, PSp, out);
    k_dft2g<<<dim3(TCH2, BB), 256, 0, stream>>>(PSp, mRe0, mIm0, mRe1, mIm1, x, out);
}

// Round 4
// 91.010 us; speedup vs baseline: 3.4053x; 1.1666x over previous
//
#include <hip/hip_runtime.h>
#include <math.h>

#define MM 2049
#define BB 16
#define NN 512
#define JH 1025           // half-spectrum (j = 0..1024)
#define JP 1040           // padded row stride for PSp (float2 units)
#define SZ 8              // s-pair-chunk split in phase 1
#define PCH 128           // pairs per chunk: 8*128 = 1024 pairs (s=1..1024)
#define JCH 5             // j-chunks of 256 (5*256 >= 1025)
// k_dft2g v2 decomposition: 16 t per block x 16 j-splits = 256 threads
#define TB 16             // t-values per block
#define JS 16             // j-splits per t (shfl-reduced)
#define JSL 65            // j per split: 16*65 = 1040 >= 1025
#define NTC 65            // t-chunks: 65*16 = 1040 >= 1025

static constexpr double D_TWO_PI    = 6.283185307179586476925286766559;
static constexpr double D_STEP      = D_TWO_PI / 2049.0;
static constexpr float  F_TWO_PI    = 6.28318530717958647692f;
static constexpr float  INV_4TAU    = 83333.33333333333f;   // 1/(4*3e-6)
static constexpr float  PI_OVER_TAU = 1047197.5511965977f;  // pi/tau
static constexpr float  TWO_TAU     = 6.0e-6f;              // 2*tau
static constexpr float  INV_2PI     = 0.15915494309189533f;
static constexpr float  INV_M       = 1.0f / 2049.0f;
static constexpr float  WINF        = 8.0f;

// ---------------------------------------------------------------------------
// Round-3 post-mortem: fused k_dft2g at 80 blocks = 1 wave/SIMD exposed the
// full ds_read latency of the 1025-iter serial rotation chain (39.9 us,
// VALUBusy 7.4%, Occ 2.5%). v2 splits each t's j-sum across 16 lanes
// (chain 1025 -> 65) and grows the grid to 1040 blocks (4 waves/SIMD),
// combining partials with in-wave __shfl_xor. Work is unchanged (~3.4 us
// of FLOPs at vector ceiling); this is purely a latency-hiding fix.
// ---------------------------------------------------------------------------

// ------------------------------------- spread + DFT1 (s-symmetry folded) ----
__global__ void k_sdft1(const float* __restrict__ x, float2* __restrict__ PSp,
                        float* __restrict__ out) {
    __shared__ float  LA[PCH];
    __shared__ float  LB[PCH];
    __shared__ float2 SD[PCH];   // {sum, diff}
    __shared__ float  Lz;        // red[0] (z==0 only)
    const int b  = blockIdx.y;
    const int z  = blockIdx.z;
    const int a0 = 1 + PCH * z;            // A = [a0, a0+PCH-1]  subset of [1,1024]
    const int b0 = 2049 - PCH * (z + 1);   // B = [b0, b0+PCH-1]  mirror (2049-s)
    // zero the output slice for batch b (k_dft2g accumulates with atomics);
    // visible to k_dft2g across the dispatch boundary.
    if (blockIdx.x == 0 && z == 0) {
        for (int i = threadIdx.x; i < NN * 2; i += 256) out[b * NN * 2 + i] = 0.0f;
    }
    for (int i = threadIdx.x; i < PCH; i += 256) { LA[i] = 0.0f; LB[i] = 0.0f; }
    if (threadIdx.x == 0) Lz = 0.0f;
    __syncthreads();
    for (int n = threadIdx.x; n < NN; n += 256) {
        float xv = x[b * NN + n];
        float xa = xv * F_TWO_PI;
        float p  = xv * (float)MM;
        int m0 = (int)ceilf(p - WINF);  if (m0 < 0) m0 = 0;
        int m1 = (int)floorf(p + WINF); if (m1 > MM - 1) m1 = MM - 1;
        bool hitA = (m1 >= a0) && (m0 <= a0 + PCH - 1);
        bool hitB = (m1 >= b0) && (m0 <= b0 + PCH - 1);
        bool hit0 = (z == 0) && (m0 == 0);
        if (!(hitA || hitB || hit0)) continue;
        for (int m = m0; m <= m1; ++m) {
            float xg = (float)((double)m * D_STEP);
            float d  = xa - xg;
            float g  = expf(-(d * d) * INV_4TAU);
            unsigned ia = (unsigned)(m - a0);
            unsigned ib = (unsigned)(m - b0);
            if (ia < PCH) atomicAdd(&LA[ia], g);
            if (ib < PCH) atomicAdd(&LB[ib], g);
            if (hit0 && m == 0) atomicAdd(&Lz, g);
        }
    }
    __syncthreads();
    // fold: pair of s=a0+i is s'=2049-a0-i = b0 + (PCH-1-i)
    for (int i = threadIdx.x; i < PCH; i += 256) {
        float ra = LA[i], rb = LB[PCH - 1 - i];
        SD[i] = make_float2(ra + rb, ra - rb);
    }
    __syncthreads();
    const int j = blockIdx.x * 256 + threadIdx.x;
    if (j >= JH) return;
    float ct, st;   // rotation step e^{i*2pi*j/M}
    { float ang = (float)((double)j * D_STEP); __sincosf(ang, &st, &ct); }
    float c, s;     // phase at s = a0
    { int r0 = (j * a0) % MM; float ph = (float)((double)r0 * D_STEP); __sincosf(ph, &s, &c); }
    float accc = 0.0f, accs = 0.0f;
    #pragma unroll 4
    for (int i = 0; i < PCH; ++i) {
        float2 sd = SD[i];                  // LDS broadcast b64
        accc = fmaf(sd.x, c, accc);
        accs = fmaf(sd.y, s, accs);
        float t1 = s * st, t2 = s * ct;
        float cn = fmaf(c, ct, -t1);
        float sn = fmaf(c, st,  t2);
        c = cn; s = sn;
    }
    if (z == 0) accc += Lz;                 // s = 0 term (cos=1, sin=0)
    PSp[((size_t)b * SZ + z) * JP + j] = make_float2(accc, accs);
}

// --------------------- mid + DFT2 (full j-sum per t-chunk) + fused gather ----
// Block (tc, b): t in [tc*16, tc*16+15]. Each t's j-sum is split across 16
// lanes (65 j each), reduced with in-wave shfl_xor. Final irf values for the
// block's m-ownership {t} u {M-t} land in LDS; the block then gathers every
// point of batch b whose window overlaps and atomicAdds into out.
__global__ __launch_bounds__(256)
void k_dft2g(const float2* __restrict__ PSp,
             const float* __restrict__ mRe0, const float* __restrict__ mIm0,
             const float* __restrict__ mRe1, const float* __restrict__ mIm1,
             const float* __restrict__ x, float* __restrict__ out) {
    __shared__ float4 lab[JH];       // 16400 B: {A0, A1, Bd0, Bd1} per j
    __shared__ float2 irfL[TB];      // irf at m = t0+i       (ch0, ch1)
    __shared__ float2 irfH[TB];      // irf at m = MM-(t0+i)  (ch0, ch1)
    const int tc  = blockIdx.x;      // 0..64
    const int b   = blockIdx.y;      // 0..15
    const int t0  = tc * TB;
    const int tid = threadIdx.x;

    // stage weighted spectral coefficients (fold the 8 s-partials, apply
    // deconv^2 * mult channel-swapped) for ALL j
    for (int i = tid; i < JH; i += 256) {
        const int j = i;
        float cs = 0.0f, sn = 0.0f;
        const float2* base = PSp + (size_t)b * SZ * JP + j;
        #pragma unroll
        for (int z = 0; z < SZ; ++z) {
            float2 ps = base[(size_t)z * JP];
            cs += ps.x; sn += ps.y;
        }
        const int msh = j + 1024;
        const float jf = (float)j;
        const float d2 = PI_OVER_TAU * expf(jf * jf * TWO_TAU);
        const float fac = (j == 0) ? 1.0f : 2.0f;
        const float sc = INV_2PI * d2 * fac;
        float4 v;
        v.x =  sc * mRe1[msh] * cs;   // A  ch0 (channel swap from ifftshift)
        v.y =  sc * mRe0[msh] * cs;   // A  ch1
        v.z = -sc * mIm1[msh] * sn;   // Bd ch0
        v.w = -sc * mIm0[msh] * sn;   // Bd ch1
        lab[i] = v;
    }
    __syncthreads();

    // per-t j-sum, 16-way lane-split
    {
        const int q  = tid & (JS - 1);   // j-sixteenth 0..15
        const int tt = tid >> 4;         // t index in block 0..15
        const int t  = t0 + tt;          // may exceed JH-1 in last chunk
        const int j0 = q * JSL;
        const int j1 = min(j0 + JSL, JH);
        float ct, st;   // rotation step e^{i*2pi*t/M}
        { float ang = (float)((double)t * D_STEP); __sincosf(ang, &st, &ct); }
        float c, s;     // phase at j = j0
        { int r0 = (t * j0) % MM; float ph = (float)((double)r0 * D_STEP); __sincosf(ph, &s, &c); }
        float E0 = 0.0f, O0 = 0.0f, E1 = 0.0f, O1 = 0.0f;
        #pragma unroll 4
        for (int i = j0; i < j1; ++i) {
            float4 v = lab[i];           // 16 distinct b128 addrs/wave, 2-way max
            E0 = fmaf(v.x, c, E0);
            O0 = fmaf(v.z, s, O0);
            E1 = fmaf(v.y, c, E1);
            O1 = fmaf(v.w, s, O1);
            float t1 = s * st, t2 = s * ct;
            float cn = fmaf(c, ct, -t1);
            float sn2 = fmaf(c, st,  t2);
            c = cn; s = sn2;
        }
        // reduce the 16 j-split partials (lanes differ only in bits 0..3)
        #pragma unroll
        for (int off = 8; off > 0; off >>= 1) {
            E0 += __shfl_xor(E0, off);
            O0 += __shfl_xor(O0, off);
            E1 += __shfl_xor(E1, off);
            O1 += __shfl_xor(O1, off);
        }
        if (q == 0 && t < JH) {
            irfL[tt] = make_float2((E0 - O0) * INV_M, (E1 - O1) * INV_M);
            irfH[tt] = make_float2((E0 + O0) * INV_M, (E1 + O1) * INV_M); // m = MM-t (t>=1)
        }
    }
    __syncthreads();

    // fused gather over this block's m-ownership
    const int L1 = min(t0 + TB, JH) - 1;                // m = t range [t0, L1]
    const int L0 = t0;
    const int H0 = MM - L1, H1 = MM - max(t0, 1);       // m = MM - t, t >= 1
    for (int n = tid; n < NN; n += 256) {
        const int p = b * NN + n;
        float xv = x[p];
        float xa = xv * F_TWO_PI;
        float pp = xv * (float)MM;
        int m0 = (int)ceilf(pp - WINF);  if (m0 < 0) m0 = 0;
        int m1 = (int)floorf(pp + WINF); if (m1 > MM - 1) m1 = MM - 1;
        float a0 = 0.0f, a1 = 0.0f;
        int lo = max(m0, L0), hi = min(m1, L1);
        for (int m = lo; m <= hi; ++m) {
            float xg = (float)((double)m * D_STEP);
            float d  = xa - xg;
            float g  = expf(-(d * d) * INV_4TAU);
            float2 v = irfL[m - L0];
            a0 = fmaf(g, v.x, a0);
            a1 = fmaf(g, v.y, a1);
        }
        int lo2 = max(m0, H0), hi2 = min(m1, H1);
        for (int m = lo2; m <= hi2; ++m) {
            float xg = (float)((double)m * D_STEP);
            float d  = xa - xg;
            float g  = expf(-(d * d) * INV_4TAU);
            float2 v = irfH[(MM - m) - t0];
            a0 = fmaf(g, v.x, a0);
            a1 = fmaf(g, v.y, a1);
        }
        if ((hi >= lo) || (hi2 >= lo2)) {
            atomicAdd(&out[p * 2 + 0], a0 * INV_M);
            atomicAdd(&out[p * 2 + 1], a1 * INV_M);
        }
    }
}

// ---------------------------------------------------------------- launch ----
extern "C" void kernel_launch(void* const* d_in, const int* in_sizes, int n_in,
                              void* d_out, int out_size, void* d_ws, size_t ws_size,
                              hipStream_t stream) {
    const float* x    = (const float*)d_in[0];
    const float* mRe0 = (const float*)d_in[1];
    const float* mIm0 = (const float*)d_in[2];
    const float* mRe1 = (const float*)d_in[3];
    const float* mIm1 = (const float*)d_in[4];
    float* out = (float*)d_out;

    float2* PSp = (float2*)d_ws;    // [BB][SZ][JP] float2

    k_sdft1<<<dim3(JCH, BB, SZ), 256, 0, stream>>>(x, PSp, out);
    k_dft2g<<<dim3(NTC, BB), 256, 0, stream>>>(PSp, mRe0, mIm0, mRe1, mIm1, x, out);
}